// Round 6
// baseline (168.840 us; speedup 1.0000x reference)
//
#include <hip/hip_runtime.h>

typedef __bf16 bf16;
typedef __attribute__((ext_vector_type(8))) __bf16 bf16x8;
typedef __attribute__((ext_vector_type(4))) __bf16 bf16x4;
typedef __attribute__((ext_vector_type(4))) float f32x4;
typedef __attribute__((ext_vector_type(2))) unsigned int uint2v;
typedef __attribute__((ext_vector_type(4))) unsigned int uint4v;

#define MFMA(a, b, c) __builtin_amdgcn_mfma_f32_16x16x32_bf16((a), (b), (c), 0, 0, 0)
#define LOG2E 1.44269504088896340736f

__device__ __forceinline__ bf16x8 cvt8(float4 a, float4 b) {
  bf16x8 r;
  r[0] = (bf16)a.x; r[1] = (bf16)a.y; r[2] = (bf16)a.z; r[3] = (bf16)a.w;
  r[4] = (bf16)b.x; r[5] = (bf16)b.y; r[6] = (bf16)b.z; r[7] = (bf16)b.w;
  return r;
}

// async global->LDS, 16B per lane. LDS dest = wave-uniform base + lane*16.
__device__ __forceinline__ void stage16(const bf16* g, bf16* l) {
  __builtin_amdgcn_global_load_lds(
      (const __attribute__((address_space(1))) void*)g,
      (__attribute__((address_space(3))) void*)l, 16, 0, 0);
}

// ---------------------------------------------------------------------------
// Kernel 0: cast X -> bf16; cast+transpose W -> bf16 W^T[n][k] (3 matrices).
// ---------------------------------------------------------------------------
__global__ __launch_bounds__(256)
void cvt(const float* __restrict__ hs, const float* __restrict__ qw,
         const float* __restrict__ kw, const float* __restrict__ vw,
         bf16* __restrict__ Xb, bf16* __restrict__ Wt) {
  const int bid = blockIdx.x, tid = threadIdx.x;
  if (bid < 2048) {               // X: 4096x1024 fp32 -> bf16, 8 elems/thread
    size_t off = (size_t)bid * 2048 + tid * 8;
    float4 x0 = *(const float4*)(hs + off);
    float4 x1 = *(const float4*)(hs + off + 4);
    *(bf16x8*)(Xb + off) = cvt8(x0, x1);
  } else {                        // W transpose: 64x64 tiles via LDS
    int t = bid - 2048;           // 0..767
    int z = t >> 8, ti = t & 255;
    const float* W = (z == 0) ? qw : (z == 1) ? kw : vw;
    int k0 = (ti >> 4) * 64, n0 = (ti & 15) * 64;
    __shared__ bf16 T[64 * 72];   // [n][k], pad 72 (16B-aligned rows)
    #pragma unroll
    for (int i = 0; i < 16; ++i) {
      int e = i * 256 + tid;
      int kr = e >> 6, nc = e & 63;
      T[nc * 72 + kr] = (bf16)W[(size_t)(k0 + kr) * 1024 + n0 + nc];
    }
    __syncthreads();
    #pragma unroll
    for (int i = 0; i < 2; ++i) {
      int e = i * 256 + tid;
      int nr = e >> 3, kg = e & 7;
      *(bf16x8*)(Wt + (size_t)z * 1048576 + (size_t)(n0 + nr) * 1024 + k0 + kg * 8) =
          *(const bf16x8*)&T[nr * 72 + kg * 8];
    }
  }
}

// ---------------------------------------------------------------------------
// Kernel 1: QKV GEMM (m97-style). 128x128 tile, 4 waves 2x2, BK=64,
// global_load_lds w=16, XOR-granule swizzle on the global-address side.
// Q pre-scaled by 0.125*log2e. V written TRANSPOSED [B,H,64,S].
// NEW: V^T epilogue bounces through LDS so global stores are coalesced
// (was: 64-lane 8B stores at 4KB stride = worst-case sector scatter).
// ---------------------------------------------------------------------------
__global__ __launch_bounds__(256, 3)
void qkv_gemm(const bf16* __restrict__ Xb, const bf16* __restrict__ Wt,
              const float* __restrict__ qbias, const float* __restrict__ kbias,
              const float* __restrict__ vbias,
              bf16* __restrict__ qo, bf16* __restrict__ ko, bf16* __restrict__ vo) {
  const int blk = blockIdx.x;           // 0..767
  const int xcd = blk & 7, slot = blk >> 3;   // slot 0..95
  const int mb = xcd * 4 + slot / 24;   // 0..31 (mb-band per XCD)
  const int nb = slot % 24;             // 0..23
  const int z = nb >> 3, nbm = nb & 7;
  const bf16* W = Wt + (size_t)z * 1048576;

  const int tid = threadIdx.x;
  const int wave = tid >> 6, lane = tid & 63, quad = lane >> 4, c = lane & 15;
  const int wr = wave >> 1, wc = wave & 1;
  const int lrow = lane >> 3;                 // 0..7 within the 8-row group
  const int lg = (lane & 7) ^ lrow;           // swizzled source granule

  // shared pool: As(16KB) + Bs(16KB) during the loop; reused as the 34KB
  // transpose bounce buffer Ts[128][136] in the z==2 epilogue.
  __shared__ __align__(16) bf16 SH[128 * 136];
  bf16* As = SH;                              // [m][k], granule g at pos g^(m&7)
  bf16* Bs = SH + 8192;                       // [n][k], same swizzle

  f32x4 acc[4][4] = {};

  for (int k0 = 0; k0 < 1024; k0 += 64) {
    #pragma unroll
    for (int i = 0; i < 4; ++i) {
      int r = wave * 32 + i * 8;              // base row (mult of 8)
      stage16(Xb + (size_t)(mb * 128 + r + lrow) * 1024 + k0 + lg * 8, &As[r * 64]);
      stage16(W + (size_t)(nbm * 128 + r + lrow) * 1024 + k0 + lg * 8, &Bs[r * 64]);
    }
    __syncthreads();
    #pragma unroll
    for (int ch = 0; ch < 2; ++ch) {
      bf16x8 af[4];
      #pragma unroll
      for (int rt = 0; rt < 4; ++rt) {
        int row = wr * 64 + rt * 16 + c;      // row&7 == c&7
        af[rt] = *(const bf16x8*)&As[row * 64 + ((((ch << 2) | quad) ^ (c & 7)) << 3)];
      }
      #pragma unroll
      for (int nt = 0; nt < 4; ++nt) {
        int row = wc * 64 + nt * 16 + c;
        bf16x8 bfrag = *(const bf16x8*)&Bs[row * 64 + ((((ch << 2) | quad) ^ (c & 7)) << 3)];
        #pragma unroll
        for (int rt = 0; rt < 4; ++rt)
          acc[rt][nt] = MFMA(af[rt], bfrag, acc[rt][nt]);
      }
    }
    __syncthreads();
  }

  const float* bias = (z == 0) ? qbias : (z == 1) ? kbias : vbias;
  float bv[4];
  #pragma unroll
  for (int nt = 0; nt < 4; ++nt)
    bv[nt] = bias[nbm * 128 + wc * 64 + nt * 16 + c];

  if (z == 2) {
    // V^T via LDS bounce: Ts[n_local][s_local], stride 136 (272B rows:
    // 16B-aligned; write banks (4c+2q)%32 -> <=2-way).
    #pragma unroll
    for (int rt = 0; rt < 4; ++rt)
      #pragma unroll
      for (int nt = 0; nt < 4; ++nt) {
        bf16x4 pk;
        #pragma unroll
        for (int reg = 0; reg < 4; ++reg) pk[reg] = (bf16)(acc[rt][nt][reg] + bv[nt]);
        int nl = wc * 64 + nt * 16 + c;            // h_loc*64 + d
        int sl = wr * 64 + rt * 16 + 4 * quad;     // s within tile
        *(bf16x4*)&SH[nl * 136 + sl] = pk;
      }
    __syncthreads();
    // coalesced store: thread pair covers one (h,d) row, 128 s * 2B = 256B
    const int row = tid >> 1, sc = tid & 1;        // row = hloc*64+d
    const int hloc = row >> 6, d = row & 63;
    const int bq = mb >> 4;                        // batch (uniform per WG)
    const int sg = (mb * 128) & 2047;              // s base within batch
    bf16* dst = vo + (((size_t)bq * 16 + nbm * 2 + hloc) * 64 + d) * 2048 + sg + sc * 64;
    #pragma unroll
    for (int j = 0; j < 8; ++j)
      *(bf16x8*)&dst[j * 8] = *(const bf16x8*)&SH[row * 136 + sc * 64 + j * 8];
  } else {
    bf16* dst = (z == 0) ? qo : ko;
    const float scale = (z == 0) ? 0.125f * LOG2E : 1.0f;  // fold 1/sqrt(d)*log2e into Q
    #pragma unroll
    for (int rt = 0; rt < 4; ++rt)
      #pragma unroll
      for (int nt = 0; nt < 4; ++nt)
        #pragma unroll
        for (int reg = 0; reg < 4; ++reg) {
          float v = (acc[rt][nt][reg] + bv[nt]) * scale;
          int m = mb * 128 + wr * 64 + rt * 16 + 4 * quad + reg;
          int n = nbm * 128 + wc * 64 + nt * 16 + c;
          int b = m >> 11, s = m & 2047, h = n >> 6, d = n & 63;
          dst[(((size_t)b * 16 + h) * 2048 + s) * 64 + d] = (bf16)v;
        }
  }
}

// ---------------------------------------------------------------------------
// Kernel 2: attention. KVBLK=128 per barrier-epoch as TWO sequential 64-key
// sub-tiles (identical r5 data path per sub-tile, VGPRs reused across kh):
// per-epoch overhead (vmcnt drain + barrier rendezvous, ~1900cyc) amortized
// over 2x work -> 16 epochs instead of 32. LDS 72KB -> 2 WG/CU (residency
// unchanged: grid 512 x 4 waves = 8 waves/CU is the grid-imposed cap).
// Double-buffer, stage-after-barrier; permlane P-transpose; mask-seeded
// accumulators; setprio around MFMA clusters.
// ---------------------------------------------------------------------------
__global__ __launch_bounds__(256, 2)
void attn(const bf16* __restrict__ qg, const bf16* __restrict__ kg,
          const bf16* __restrict__ vtg, const float* __restrict__ mask,
          float* __restrict__ out) {
  const int blk = blockIdx.x;                // 0..511
  const int xcd = blk & 7, slot = blk >> 3;  // slot 0..63
  const int bh = xcd * 4 + (slot >> 4);      // 4 bh per XCD (K/V pinned in L2)
  const int qblk = slot & 15;                // 16 qblks x 128 rows
  const int b = bh >> 4, h = bh & 15;
  const int tid = threadIdx.x;
  const int wave = tid >> 6, lane = tid & 63, quad = lane >> 4, c = lane & 15;
  const int lrow = lane >> 3, lg = (lane & 7) ^ lrow;

  __shared__ __align__(16) bf16 Ks[2][2][64 * 64];  // [buf][kh][key][d]
  __shared__ __align__(16) bf16 Vs[2][2][64 * 64];  // [buf][kh][d][key]
  __shared__ __align__(16) float Ms[2048];          // mask*log2e

  const bf16* qb_ = qg + (size_t)bh * 2048 * 64;
  const bf16* kb_ = kg + (size_t)bh * 2048 * 64;
  const bf16* vb_ = vtg + (size_t)bh * 64 * 2048;

  // ---- prologue: mask -> LDS (pre-scaled), Q frags, stage tile 0 ----
  #pragma unroll
  for (int i = 0; i < 2; ++i) {
    int idx = i * 1024 + tid * 4;
    float4 m = *(const float4*)&mask[b * 2048 + idx];
    float4 ms = {m.x * LOG2E, m.y * LOG2E, m.z * LOG2E, m.w * LOG2E};
    *(float4*)&Ms[idx] = ms;
  }

  bf16x8 qf[2][2];   // Q pre-scaled by 0.125*log2e; wave owns rows wave*32+ct*16+c
  #pragma unroll
  for (int ct = 0; ct < 2; ++ct)
    #pragma unroll
    for (int ch = 0; ch < 2; ++ch)
      qf[ct][ch] = *(const bf16x8*)(qb_ +
          (size_t)(qblk * 128 + wave * 32 + ct * 16 + c) * 64 + ch * 32 + quad * 8);

  #pragma unroll
  for (int kh = 0; kh < 2; ++kh)
    #pragma unroll
    for (int i = 0; i < 2; ++i) {   // wave stages 16 K rows + 16 V rows per kh
      int r = wave * 16 + i * 8;
      stage16(kb_ + (size_t)(kh * 64 + r + lrow) * 64 + lg * 8, &Ks[0][kh][r * 64]);
      stage16(vb_ + (size_t)(r + lrow) * 2048 + kh * 64 + lg * 8, &Vs[0][kh][r * 64]);
    }
  __asm__ volatile("s_waitcnt lgkmcnt(0)" ::: "memory");  // mask ds_writes done

  f32x4 o[2][4] = {};     // o[ct][nt][reg] = O[q=ct*16+c][d=nt*16+4*quad+reg]
  float lsum[2] = {0.f, 0.f};

  for (int kt = 0; kt < 16; ++kt) {
    const int cur = kt & 1;
    // own stage(kt) loads are the only outstanding VMEM: drain (1 epoch cover)
    __asm__ volatile("s_waitcnt vmcnt(0)" ::: "memory");
    __builtin_amdgcn_s_barrier();
    __builtin_amdgcn_sched_barrier(0);   // nothing hoists above the barrier

    if (kt < 15) {                       // stage tile kt+1 (128 keys) into other buf
      #pragma unroll
      for (int kh = 0; kh < 2; ++kh)
        #pragma unroll
        for (int i = 0; i < 2; ++i) {
          int r = wave * 16 + i * 8;
          stage16(kb_ + (size_t)((kt + 1) * 128 + kh * 64 + r + lrow) * 64 + lg * 8,
                  &Ks[cur ^ 1][kh][r * 64]);
          stage16(vb_ + (size_t)(r + lrow) * 2048 + (kt + 1) * 128 + kh * 64 + lg * 8,
                  &Vs[cur ^ 1][kh][r * 64]);
        }
    }
    __builtin_amdgcn_sched_barrier(0);   // staging issued before compute

    #pragma unroll
    for (int kh = 0; kh < 2; ++kh) {
      // ---- seed S^T accumulators with mask (key-indexed = S^T row) ----
      f32x4 s[2][4];
      #pragma unroll
      for (int nt = 0; nt < 4; ++nt) {
        float4 mv = *(const float4*)&Ms[kt * 128 + kh * 64 + nt * 16 + 4 * quad];
        f32x4 sv = {mv.x, mv.y, mv.z, mv.w};
        s[0][nt] = sv;
        s[1][nt] = sv;
      }

      // ---- S^T = K Q^T + mask ----
      __builtin_amdgcn_s_setprio(1);
      #pragma unroll
      for (int nt = 0; nt < 4; ++nt)
        #pragma unroll
        for (int ch = 0; ch < 2; ++ch) {
          bf16x8 kf = *(const bf16x8*)&Ks[cur][kh][(nt * 16 + c) * 64 +
                                              ((((ch << 2) | quad) ^ (c & 7)) << 3)];
          s[0][nt] = MFMA(kf, qf[0][ch], s[0][nt]);
          s[1][nt] = MFMA(kf, qf[1][ch], s[1][nt]);
        }
      __builtin_amdgcn_s_setprio(0);

      // ---- p = exp2(s); pack to bf16 dwords; quad-transpose in regs ----
      // Lane(quad,c) holds P[key=nt*16+4*quad+reg][q=c]; PV needs
      // P[key=ch*32+8*quad..+7][q=c]. (P0,P2)=pl16swap(pl32swap(X0,Y0)).
      bf16x8 pa[2][2];
      #pragma unroll
      for (int ct = 0; ct < 2; ++ct) {
        unsigned int U[4][2];
        #pragma unroll
        for (int nt = 0; nt < 4; ++nt) {
          bf16x4 pk;
          #pragma unroll
          for (int reg = 0; reg < 4; ++reg) {
            float p = __builtin_amdgcn_exp2f(s[ct][nt][reg]);
            lsum[ct] += p;
            pk[reg] = (bf16)p;
          }
          uint2v uu = __builtin_bit_cast(uint2v, pk);
          U[nt][0] = uu.x; U[nt][1] = uu.y;
        }
        #pragma unroll
        for (int ch = 0; ch < 2; ++ch) {
          unsigned int X0 = U[2 * ch][0],     X1 = U[2 * ch][1];
          unsigned int Y0 = U[2 * ch + 1][0], Y1 = U[2 * ch + 1][1];
          __asm__ volatile("v_permlane32_swap_b32 %0, %1" : "+v"(X0), "+v"(Y0));
          __asm__ volatile("v_permlane32_swap_b32 %0, %1" : "+v"(X1), "+v"(Y1));
          __asm__ volatile("v_permlane16_swap_b32 %0, %1" : "+v"(X0), "+v"(Y0));
          __asm__ volatile("v_permlane16_swap_b32 %0, %1" : "+v"(X1), "+v"(Y1));
          uint4v up = {X0, X1, Y0, Y1};
          pa[ct][ch] = __builtin_bit_cast(bf16x8, up);
        }
      }

      // ---- O^T += V^T P^T ----
      __builtin_amdgcn_s_setprio(1);
      #pragma unroll
      for (int ch = 0; ch < 2; ++ch)
        #pragma unroll
        for (int nt = 0; nt < 4; ++nt) {
          bf16x8 vf = *(const bf16x8*)&Vs[cur][kh][(nt * 16 + c) * 64 +
                                              ((((ch << 2) | quad) ^ (c & 7)) << 3)];
          o[0][nt] = MFMA(vf, pa[0][ch], o[0][nt]);
          o[1][nt] = MFMA(vf, pa[1][ch], o[1][nt]);
        }
      __builtin_amdgcn_s_setprio(0);
    }
  }

  // ---- l reduce over the 4 quads sharing q, normalize, float4 store ----
  #pragma unroll
  for (int ct = 0; ct < 2; ++ct) {
    float l = lsum[ct];
    l += __shfl_xor(l, 16, 64);
    l += __shfl_xor(l, 32, 64);
    const float inv = 1.0f / l;
    const int srow = qblk * 128 + wave * 32 + ct * 16 + c;
    #pragma unroll
    for (int nt = 0; nt < 4; ++nt) {
      float4 st = { o[ct][nt][0] * inv, o[ct][nt][1] * inv,
                    o[ct][nt][2] * inv, o[ct][nt][3] * inv };
      *(float4*)&out[((size_t)b * 2048 + srow) * 1024 + h * 64 + nt * 16 + 4 * quad] = st;
    }
  }
}

// ---------------------------------------------------------------------------
extern "C" void kernel_launch(void* const* d_in, const int* in_sizes, int n_in,
                              void* d_out, int out_size, void* d_ws, size_t ws_size,
                              hipStream_t stream) {
  const float* hs   = (const float*)d_in[0];
  const float* mask = (const float*)d_in[1];
  const float* qw   = (const float*)d_in[2];
  const float* qb   = (const float*)d_in[3];
  const float* kw   = (const float*)d_in[4];
  const float* kb   = (const float*)d_in[5];
  const float* vw   = (const float*)d_in[6];
  const float* vb   = (const float*)d_in[7];
  float* out = (float*)d_out;

  bf16* Xb   = (bf16*)d_ws;                       // 4096x1024      (8 MB)
  bf16* Wt   = Xb + (size_t)4096 * 1024;          // 3x1024x1024    (6 MB)
  bf16* q_ws = Wt + (size_t)3 * 1048576;          // [B,H,S,64]     (8 MB)
  bf16* k_ws = q_ws + (size_t)4096 * 1024;        // [B,H,S,64]     (8 MB)
  bf16* v_ws = k_ws + (size_t)4096 * 1024;        // [B,H,64,S] V^T (8 MB)

  cvt<<<dim3(2816), 256, 0, stream>>>(hs, qw, kw, vw, Xb, Wt);
  qkv_gemm<<<dim3(768), 256, 0, stream>>>(Xb, Wt, qb, kb, vb, q_ws, k_ws, v_ws);
  attn<<<dim3(512), 256, 0, stream>>>(q_ws, k_ws, v_ws, mask, out);
}

// Round 7
// 165.157 us; speedup vs baseline: 1.0223x; 1.0223x over previous
//
#include <hip/hip_runtime.h>

typedef __bf16 bf16;
typedef __attribute__((ext_vector_type(8))) __bf16 bf16x8;
typedef __attribute__((ext_vector_type(4))) __bf16 bf16x4;
typedef __attribute__((ext_vector_type(4))) float f32x4;
typedef __attribute__((ext_vector_type(2))) unsigned int uint2v;
typedef __attribute__((ext_vector_type(4))) unsigned int uint4v;

#define MFMA(a, b, c) __builtin_amdgcn_mfma_f32_16x16x32_bf16((a), (b), (c), 0, 0, 0)
#define LOG2E 1.44269504088896340736f

__device__ __forceinline__ bf16x8 cvt8(float4 a, float4 b) {
  bf16x8 r;
  r[0] = (bf16)a.x; r[1] = (bf16)a.y; r[2] = (bf16)a.z; r[3] = (bf16)a.w;
  r[4] = (bf16)b.x; r[5] = (bf16)b.y; r[6] = (bf16)b.z; r[7] = (bf16)b.w;
  return r;
}

// async global->LDS, 16B per lane. LDS dest = wave-uniform base + lane*16.
__device__ __forceinline__ void stage16(const bf16* g, bf16* l) {
  __builtin_amdgcn_global_load_lds(
      (const __attribute__((address_space(1))) void*)g,
      (__attribute__((address_space(3))) void*)l, 16, 0, 0);
}

// ---------------------------------------------------------------------------
// Kernel 0: cast X -> bf16; cast+transpose W -> bf16 W^T[n][k] (3 matrices).
// ---------------------------------------------------------------------------
__global__ __launch_bounds__(256)
void cvt(const float* __restrict__ hs, const float* __restrict__ qw,
         const float* __restrict__ kw, const float* __restrict__ vw,
         bf16* __restrict__ Xb, bf16* __restrict__ Wt) {
  const int bid = blockIdx.x, tid = threadIdx.x;
  if (bid < 2048) {               // X: 4096x1024 fp32 -> bf16, 8 elems/thread
    size_t off = (size_t)bid * 2048 + tid * 8;
    float4 x0 = *(const float4*)(hs + off);
    float4 x1 = *(const float4*)(hs + off + 4);
    *(bf16x8*)(Xb + off) = cvt8(x0, x1);
  } else {                        // W transpose: 64x64 tiles via LDS
    int t = bid - 2048;           // 0..767
    int z = t >> 8, ti = t & 255;
    const float* W = (z == 0) ? qw : (z == 1) ? kw : vw;
    int k0 = (ti >> 4) * 64, n0 = (ti & 15) * 64;
    __shared__ bf16 T[64 * 72];   // [n][k], pad 72 (16B-aligned rows)
    #pragma unroll
    for (int i = 0; i < 16; ++i) {
      int e = i * 256 + tid;
      int kr = e >> 6, nc = e & 63;
      T[nc * 72 + kr] = (bf16)W[(size_t)(k0 + kr) * 1024 + n0 + nc];
    }
    __syncthreads();
    #pragma unroll
    for (int i = 0; i < 2; ++i) {
      int e = i * 256 + tid;
      int nr = e >> 3, kg = e & 7;
      *(bf16x8*)(Wt + (size_t)z * 1048576 + (size_t)(n0 + nr) * 1024 + k0 + kg * 8) =
          *(const bf16x8*)&T[nr * 72 + kg * 8];
    }
  }
}

// ---------------------------------------------------------------------------
// Kernel 1: QKV GEMM (m97-style). 128x128 tile, 4 waves 2x2, BK=64,
// global_load_lds w=16, XOR-granule swizzle on the global-address side.
// Q pre-scaled by 0.125*log2e. V written TRANSPOSED [B,H,64,S].
// (round-6 LDS-bounce epilogue reverted: no measured win)
// ---------------------------------------------------------------------------
__global__ __launch_bounds__(256, 3)
void qkv_gemm(const bf16* __restrict__ Xb, const bf16* __restrict__ Wt,
              const float* __restrict__ qbias, const float* __restrict__ kbias,
              const float* __restrict__ vbias,
              bf16* __restrict__ qo, bf16* __restrict__ ko, bf16* __restrict__ vo) {
  const int blk = blockIdx.x;           // 0..767
  const int xcd = blk & 7, slot = blk >> 3;   // slot 0..95
  const int mb = xcd * 4 + slot / 24;   // 0..31 (mb-band per XCD)
  const int nb = slot % 24;             // 0..23
  const int z = nb >> 3, nbm = nb & 7;
  const bf16* W = Wt + (size_t)z * 1048576;

  const int tid = threadIdx.x;
  const int wave = tid >> 6, lane = tid & 63, quad = lane >> 4, c = lane & 15;
  const int wr = wave >> 1, wc = wave & 1;
  const int lrow = lane >> 3;                 // 0..7 within the 8-row group
  const int lg = (lane & 7) ^ lrow;           // swizzled source granule

  __shared__ bf16 As[128 * 64];               // [m][k], granule g at pos g^(m&7)
  __shared__ bf16 Bs[128 * 64];               // [n][k], same swizzle

  f32x4 acc[4][4] = {};

  for (int k0 = 0; k0 < 1024; k0 += 64) {
    #pragma unroll
    for (int i = 0; i < 4; ++i) {
      int r = wave * 32 + i * 8;              // base row (mult of 8)
      stage16(Xb + (size_t)(mb * 128 + r + lrow) * 1024 + k0 + lg * 8, &As[r * 64]);
      stage16(W + (size_t)(nbm * 128 + r + lrow) * 1024 + k0 + lg * 8, &Bs[r * 64]);
    }
    __syncthreads();
    #pragma unroll
    for (int ch = 0; ch < 2; ++ch) {
      bf16x8 af[4];
      #pragma unroll
      for (int rt = 0; rt < 4; ++rt) {
        int row = wr * 64 + rt * 16 + c;      // row&7 == c&7
        af[rt] = *(const bf16x8*)&As[row * 64 + ((((ch << 2) | quad) ^ (c & 7)) << 3)];
      }
      #pragma unroll
      for (int nt = 0; nt < 4; ++nt) {
        int row = wc * 64 + nt * 16 + c;
        bf16x8 bfrag = *(const bf16x8*)&Bs[row * 64 + ((((ch << 2) | quad) ^ (c & 7)) << 3)];
        #pragma unroll
        for (int rt = 0; rt < 4; ++rt)
          acc[rt][nt] = MFMA(af[rt], bfrag, acc[rt][nt]);
      }
    }
    __syncthreads();
  }

  const float* bias = (z == 0) ? qbias : (z == 1) ? kbias : vbias;
  float bv[4];
  #pragma unroll
  for (int nt = 0; nt < 4; ++nt)
    bv[nt] = bias[nbm * 128 + wc * 64 + nt * 16 + c];

  if (z == 2) {
    // V^T: vo[((b*16+h)*64 + d)*2048 + s], packed 4 along s (= reg dim)
    #pragma unroll
    for (int rt = 0; rt < 4; ++rt)
      #pragma unroll
      for (int nt = 0; nt < 4; ++nt) {
        int m0 = mb * 128 + wr * 64 + rt * 16 + 4 * quad;
        int n = nbm * 128 + wc * 64 + nt * 16 + c;
        bf16x4 pk;
        #pragma unroll
        for (int reg = 0; reg < 4; ++reg) pk[reg] = (bf16)(acc[rt][nt][reg] + bv[nt]);
        int b = m0 >> 11, s0 = m0 & 2047, h = n >> 6, d = n & 63;
        *(bf16x4*)&vo[(((size_t)b * 16 + h) * 64 + d) * 2048 + s0] = pk;
      }
  } else {
    bf16* dst = (z == 0) ? qo : ko;
    const float scale = (z == 0) ? 0.125f * LOG2E : 1.0f;  // fold 1/sqrt(d)*log2e into Q
    #pragma unroll
    for (int rt = 0; rt < 4; ++rt)
      #pragma unroll
      for (int nt = 0; nt < 4; ++nt)
        #pragma unroll
        for (int reg = 0; reg < 4; ++reg) {
          float v = (acc[rt][nt][reg] + bv[nt]) * scale;
          int m = mb * 128 + wr * 64 + rt * 16 + 4 * quad + reg;
          int n = nbm * 128 + wc * 64 + nt * 16 + c;
          int b = m >> 11, s = m & 2047, h = n >> 6, d = n & 63;
          dst[(((size_t)b * 16 + h) * 2048 + s) * 64 + d] = (bf16)v;
        }
  }
}

// ---------------------------------------------------------------------------
// Kernel 2: attention. Occupancy round: 6 rounds showed a ~2000cyc/SIMD
// per-subtile wall at 2 waves/SIMD with all pipes ~60% idle-summed; the
// grid (512 WGs x 4 waves = 8 waves/CU) was the cap. Now: qblk=32 (64
// q-rows/WG, 16 q-rows/wave, ct loop removed), grid = 32bh x 32qblk = 1024
// WGs = 4 WG/CU x 40KB LDS = 160KB exact -> 16 waves/CU = 4 waves/SIMD.
// Cost: K/V LDS-read traffic per CU doubles (LDS pipe -> ~70-95%, i.e.
// pushed toward the LDS roofline). VGPR ~75 < 128 so 4 waves/SIMD legal.
// r5 data path kept: dbuf + stage-after-barrier + vmcnt(0) (1-iter cover),
// permlane P-transpose, mask-seeded accumulators, setprio. lsum split into
// 2 accumulators (halves the serial fadd chain).
// ---------------------------------------------------------------------------
__global__ __launch_bounds__(256, 4)
void attn(const bf16* __restrict__ qg, const bf16* __restrict__ kg,
          const bf16* __restrict__ vtg, const float* __restrict__ mask,
          float* __restrict__ out) {
  const int blk = blockIdx.x;                // 0..1023
  const int xcd = blk & 7, slot = blk >> 3;  // slot 0..127
  const int bh = xcd * 4 + (slot >> 5);      // 4 bh per XCD (K/V pinned in L2)
  const int qblk = slot & 31;                // 32 qblks x 64 rows
  const int b = bh >> 4, h = bh & 15;
  const int tid = threadIdx.x;
  const int wave = tid >> 6, lane = tid & 63, quad = lane >> 4, c = lane & 15;
  const int lrow = lane >> 3, lg = (lane & 7) ^ lrow;

  __shared__ __align__(16) bf16 Ks[2][64 * 64];  // [key][d], granule swizzle
  __shared__ __align__(16) bf16 Vs[2][64 * 64];  // [d][key], granule swizzle
  __shared__ __align__(16) float Ms[2048];       // mask*log2e

  const bf16* qb_ = qg + (size_t)bh * 2048 * 64;
  const bf16* kb_ = kg + (size_t)bh * 2048 * 64;
  const bf16* vb_ = vtg + (size_t)bh * 64 * 2048;

  // ---- prologue: mask -> LDS (pre-scaled), Q frags, stage tile 0 ----
  #pragma unroll
  for (int i = 0; i < 2; ++i) {
    int idx = i * 1024 + tid * 4;
    float4 m = *(const float4*)&mask[b * 2048 + idx];
    float4 ms = {m.x * LOG2E, m.y * LOG2E, m.z * LOG2E, m.w * LOG2E};
    *(float4*)&Ms[idx] = ms;
  }

  bf16x8 qf[2];   // Q pre-scaled by 0.125*log2e; wave owns rows wave*16+c
  #pragma unroll
  for (int ch = 0; ch < 2; ++ch)
    qf[ch] = *(const bf16x8*)(qb_ +
        (size_t)(qblk * 64 + wave * 16 + c) * 64 + ch * 32 + quad * 8);

  #pragma unroll
  for (int i = 0; i < 2; ++i) {   // wave stages 16 K rows + 16 V rows of tile 0
    int r = wave * 16 + i * 8;
    stage16(kb_ + (size_t)(r + lrow) * 64 + lg * 8, &Ks[0][r * 64]);
    stage16(vb_ + (size_t)(r + lrow) * 2048 + lg * 8, &Vs[0][r * 64]);
  }
  __asm__ volatile("s_waitcnt lgkmcnt(0)" ::: "memory");  // mask ds_writes done

  f32x4 o[4] = {};       // o[nt][reg] = O[q=c][d=nt*16+4*quad+reg]
  float lsum2[2] = {0.f, 0.f};

  for (int kt = 0; kt < 32; ++kt) {
    const int cur = kt & 1;
    // own stage(kt) loads are the only outstanding VMEM: drain (1 iter cover)
    __asm__ volatile("s_waitcnt vmcnt(0)" ::: "memory");
    __builtin_amdgcn_s_barrier();
    __builtin_amdgcn_sched_barrier(0);   // nothing hoists above the barrier

    if (kt < 31) {                       // stage tile kt+1 into the other buf
      #pragma unroll
      for (int i = 0; i < 2; ++i) {
        int r = wave * 16 + i * 8;
        stage16(kb_ + (size_t)((kt + 1) * 64 + r + lrow) * 64 + lg * 8,
                &Ks[cur ^ 1][r * 64]);
        stage16(vb_ + (size_t)(r + lrow) * 2048 + (kt + 1) * 64 + lg * 8,
                &Vs[cur ^ 1][r * 64]);
      }
    }
    __builtin_amdgcn_sched_barrier(0);   // staging issued before compute

    // ---- seed S^T accumulators with mask (key-indexed = S^T row) ----
    f32x4 s[4];
    #pragma unroll
    for (int nt = 0; nt < 4; ++nt) {
      float4 mv = *(const float4*)&Ms[kt * 64 + nt * 16 + 4 * quad];
      f32x4 sv = {mv.x, mv.y, mv.z, mv.w};
      s[nt] = sv;
    }

    // ---- S^T = K Q^T + mask ----
    __builtin_amdgcn_s_setprio(1);
    #pragma unroll
    for (int nt = 0; nt < 4; ++nt)
      #pragma unroll
      for (int ch = 0; ch < 2; ++ch) {
        bf16x8 kf = *(const bf16x8*)&Ks[cur][(nt * 16 + c) * 64 +
                                            ((((ch << 2) | quad) ^ (c & 7)) << 3)];
        s[nt] = MFMA(kf, qf[ch], s[nt]);
      }
    __builtin_amdgcn_s_setprio(0);

    // ---- p = exp2(s); pack to bf16 dwords; quad-transpose in regs ----
    // Lane(quad,c) holds P[key=nt*16+4*quad+reg][q=c]; PV needs
    // P[key=ch*32+8*quad..+7][q=c]. (P0,P2)=pl16swap(pl32swap(X0,Y0)).
    unsigned int U[4][2];
    #pragma unroll
    for (int nt = 0; nt < 4; ++nt) {
      bf16x4 pk;
      #pragma unroll
      for (int reg = 0; reg < 4; ++reg) {
        float p = __builtin_amdgcn_exp2f(s[nt][reg]);
        lsum2[nt & 1] += p;
        pk[reg] = (bf16)p;
      }
      uint2v uu = __builtin_bit_cast(uint2v, pk);
      U[nt][0] = uu.x; U[nt][1] = uu.y;
    }
    bf16x8 pa[2];
    #pragma unroll
    for (int ch = 0; ch < 2; ++ch) {
      unsigned int X0 = U[2 * ch][0],     X1 = U[2 * ch][1];
      unsigned int Y0 = U[2 * ch + 1][0], Y1 = U[2 * ch + 1][1];
      __asm__ volatile("v_permlane32_swap_b32 %0, %1" : "+v"(X0), "+v"(Y0));
      __asm__ volatile("v_permlane32_swap_b32 %0, %1" : "+v"(X1), "+v"(Y1));
      __asm__ volatile("v_permlane16_swap_b32 %0, %1" : "+v"(X0), "+v"(Y0));
      __asm__ volatile("v_permlane16_swap_b32 %0, %1" : "+v"(X1), "+v"(Y1));
      uint4v up = {X0, X1, Y0, Y1};
      pa[ch] = __builtin_bit_cast(bf16x8, up);
    }

    // ---- O^T += V^T P^T ----
    __builtin_amdgcn_s_setprio(1);
    #pragma unroll
    for (int ch = 0; ch < 2; ++ch)
      #pragma unroll
      for (int nt = 0; nt < 4; ++nt) {
        bf16x8 vf = *(const bf16x8*)&Vs[cur][(nt * 16 + c) * 64 +
                                            ((((ch << 2) | quad) ^ (c & 7)) << 3)];
        o[nt] = MFMA(vf, pa[ch], o[nt]);
      }
    __builtin_amdgcn_s_setprio(0);
  }

  // ---- l reduce over the 4 quads sharing q, normalize, float4 store ----
  {
    float l = lsum2[0] + lsum2[1];
    l += __shfl_xor(l, 16, 64);
    l += __shfl_xor(l, 32, 64);
    const float inv = 1.0f / l;
    const int srow = qblk * 64 + wave * 16 + c;
    #pragma unroll
    for (int nt = 0; nt < 4; ++nt) {
      float4 st = { o[nt][0] * inv, o[nt][1] * inv,
                    o[nt][2] * inv, o[nt][3] * inv };
      *(float4*)&out[((size_t)b * 2048 + srow) * 1024 + h * 64 + nt * 16 + 4 * quad] = st;
    }
  }
}

// ---------------------------------------------------------------------------
extern "C" void kernel_launch(void* const* d_in, const int* in_sizes, int n_in,
                              void* d_out, int out_size, void* d_ws, size_t ws_size,
                              hipStream_t stream) {
  const float* hs   = (const float*)d_in[0];
  const float* mask = (const float*)d_in[1];
  const float* qw   = (const float*)d_in[2];
  const float* qb   = (const float*)d_in[3];
  const float* kw   = (const float*)d_in[4];
  const float* kb   = (const float*)d_in[5];
  const float* vw   = (const float*)d_in[6];
  const float* vb   = (const float*)d_in[7];
  float* out = (float*)d_out;

  bf16* Xb   = (bf16*)d_ws;                       // 4096x1024      (8 MB)
  bf16* Wt   = Xb + (size_t)4096 * 1024;          // 3x1024x1024    (6 MB)
  bf16* q_ws = Wt + (size_t)3 * 1048576;          // [B,H,S,64]     (8 MB)
  bf16* k_ws = q_ws + (size_t)4096 * 1024;        // [B,H,S,64]     (8 MB)
  bf16* v_ws = k_ws + (size_t)4096 * 1024;        // [B,H,64,S] V^T (8 MB)

  cvt<<<dim3(2816), 256, 0, stream>>>(hs, qw, kw, vw, Xb, Wt);
  qkv_gemm<<<dim3(768), 256, 0, stream>>>(Xb, Wt, qb, kb, vb, q_ws, k_ws, v_ws);
  attn<<<dim3(1024), 256, 0, stream>>>(q_ws, k_ws, v_ws, mask, out);
}

// Round 8
// 161.294 us; speedup vs baseline: 1.0468x; 1.0239x over previous
//
#include <hip/hip_runtime.h>

typedef __bf16 bf16;
typedef __attribute__((ext_vector_type(8))) __bf16 bf16x8;
typedef __attribute__((ext_vector_type(4))) __bf16 bf16x4;
typedef __attribute__((ext_vector_type(4))) float f32x4;
typedef __attribute__((ext_vector_type(2))) unsigned int uint2v;
typedef __attribute__((ext_vector_type(4))) unsigned int uint4v;

#define MFMA(a, b, c) __builtin_amdgcn_mfma_f32_16x16x32_bf16((a), (b), (c), 0, 0, 0)
#define LOG2E 1.44269504088896340736f

__device__ __forceinline__ bf16x8 cvt8(float4 a, float4 b) {
  bf16x8 r;
  r[0] = (bf16)a.x; r[1] = (bf16)a.y; r[2] = (bf16)a.z; r[3] = (bf16)a.w;
  r[4] = (bf16)b.x; r[5] = (bf16)b.y; r[6] = (bf16)b.z; r[7] = (bf16)b.w;
  return r;
}

// async global->LDS, 16B per lane. LDS dest = wave-uniform base + lane*16.
__device__ __forceinline__ void stage16(const bf16* g, bf16* l) {
  __builtin_amdgcn_global_load_lds(
      (const __attribute__((address_space(1))) void*)g,
      (__attribute__((address_space(3))) void*)l, 16, 0, 0);
}

// ---------------------------------------------------------------------------
// Kernel 0: cast X -> bf16; cast+transpose W -> bf16 W^T[n][k] (3 matrices).
// ---------------------------------------------------------------------------
__global__ __launch_bounds__(256)
void cvt(const float* __restrict__ hs, const float* __restrict__ qw,
         const float* __restrict__ kw, const float* __restrict__ vw,
         bf16* __restrict__ Xb, bf16* __restrict__ Wt) {
  const int bid = blockIdx.x, tid = threadIdx.x;
  if (bid < 2048) {               // X: 4096x1024 fp32 -> bf16, 8 elems/thread
    size_t off = (size_t)bid * 2048 + tid * 8;
    float4 x0 = *(const float4*)(hs + off);
    float4 x1 = *(const float4*)(hs + off + 4);
    *(bf16x8*)(Xb + off) = cvt8(x0, x1);
  } else {                        // W transpose: 64x64 tiles via LDS
    int t = bid - 2048;           // 0..767
    int z = t >> 8, ti = t & 255;
    const float* W = (z == 0) ? qw : (z == 1) ? kw : vw;
    int k0 = (ti >> 4) * 64, n0 = (ti & 15) * 64;
    __shared__ bf16 T[64 * 72];   // [n][k], pad 72 (16B-aligned rows)
    #pragma unroll
    for (int i = 0; i < 16; ++i) {
      int e = i * 256 + tid;
      int kr = e >> 6, nc = e & 63;
      T[nc * 72 + kr] = (bf16)W[(size_t)(k0 + kr) * 1024 + n0 + nc];
    }
    __syncthreads();
    #pragma unroll
    for (int i = 0; i < 2; ++i) {
      int e = i * 256 + tid;
      int nr = e >> 3, kg = e & 7;
      *(bf16x8*)(Wt + (size_t)z * 1048576 + (size_t)(n0 + nr) * 1024 + k0 + kg * 8) =
          *(const bf16x8*)&T[nr * 72 + kg * 8];
    }
  }
}

// ---------------------------------------------------------------------------
// Kernel 1: QKV GEMM (m97-style). 128x128 tile, 4 waves 2x2, BK=64,
// global_load_lds w=16, XOR-granule swizzle on the global-address side.
// Q pre-scaled by 0.125*log2e. V written TRANSPOSED [B,H,64,S].
// ---------------------------------------------------------------------------
__global__ __launch_bounds__(256, 3)
void qkv_gemm(const bf16* __restrict__ Xb, const bf16* __restrict__ Wt,
              const float* __restrict__ qbias, const float* __restrict__ kbias,
              const float* __restrict__ vbias,
              bf16* __restrict__ qo, bf16* __restrict__ ko, bf16* __restrict__ vo) {
  const int blk = blockIdx.x;           // 0..767
  const int xcd = blk & 7, slot = blk >> 3;   // slot 0..95
  const int mb = xcd * 4 + slot / 24;   // 0..31 (mb-band per XCD)
  const int nb = slot % 24;             // 0..23
  const int z = nb >> 3, nbm = nb & 7;
  const bf16* W = Wt + (size_t)z * 1048576;

  const int tid = threadIdx.x;
  const int wave = tid >> 6, lane = tid & 63, quad = lane >> 4, c = lane & 15;
  const int wr = wave >> 1, wc = wave & 1;
  const int lrow = lane >> 3;                 // 0..7 within the 8-row group
  const int lg = (lane & 7) ^ lrow;           // swizzled source granule

  __shared__ bf16 As[128 * 64];               // [m][k], granule g at pos g^(m&7)
  __shared__ bf16 Bs[128 * 64];               // [n][k], same swizzle

  f32x4 acc[4][4] = {};

  for (int k0 = 0; k0 < 1024; k0 += 64) {
    #pragma unroll
    for (int i = 0; i < 4; ++i) {
      int r = wave * 32 + i * 8;              // base row (mult of 8)
      stage16(Xb + (size_t)(mb * 128 + r + lrow) * 1024 + k0 + lg * 8, &As[r * 64]);
      stage16(W + (size_t)(nbm * 128 + r + lrow) * 1024 + k0 + lg * 8, &Bs[r * 64]);
    }
    __syncthreads();
    #pragma unroll
    for (int ch = 0; ch < 2; ++ch) {
      bf16x8 af[4];
      #pragma unroll
      for (int rt = 0; rt < 4; ++rt) {
        int row = wr * 64 + rt * 16 + c;      // row&7 == c&7
        af[rt] = *(const bf16x8*)&As[row * 64 + ((((ch << 2) | quad) ^ (c & 7)) << 3)];
      }
      #pragma unroll
      for (int nt = 0; nt < 4; ++nt) {
        int row = wc * 64 + nt * 16 + c;
        bf16x8 bfrag = *(const bf16x8*)&Bs[row * 64 + ((((ch << 2) | quad) ^ (c & 7)) << 3)];
        #pragma unroll
        for (int rt = 0; rt < 4; ++rt)
          acc[rt][nt] = MFMA(af[rt], bfrag, acc[rt][nt]);
      }
    }
    __syncthreads();
  }

  const float* bias = (z == 0) ? qbias : (z == 1) ? kbias : vbias;
  float bv[4];
  #pragma unroll
  for (int nt = 0; nt < 4; ++nt)
    bv[nt] = bias[nbm * 128 + wc * 64 + nt * 16 + c];

  if (z == 2) {
    // V^T: vo[((b*16+h)*64 + d)*2048 + s], packed 4 along s (= reg dim)
    #pragma unroll
    for (int rt = 0; rt < 4; ++rt)
      #pragma unroll
      for (int nt = 0; nt < 4; ++nt) {
        int m0 = mb * 128 + wr * 64 + rt * 16 + 4 * quad;
        int n = nbm * 128 + wc * 64 + nt * 16 + c;
        bf16x4 pk;
        #pragma unroll
        for (int reg = 0; reg < 4; ++reg) pk[reg] = (bf16)(acc[rt][nt][reg] + bv[nt]);
        int b = m0 >> 11, s0 = m0 & 2047, h = n >> 6, d = n & 63;
        *(bf16x4*)&vo[(((size_t)b * 16 + h) * 64 + d) * 2048 + s0] = pk;
      }
  } else {
    bf16* dst = (z == 0) ? qo : ko;
    const float scale = (z == 0) ? 0.125f * LOG2E : 1.0f;  // fold 1/sqrt(d)*log2e into Q
    #pragma unroll
    for (int rt = 0; rt < 4; ++rt)
      #pragma unroll
      for (int nt = 0; nt < 4; ++nt)
        #pragma unroll
        for (int reg = 0; reg < 4; ++reg) {
          float v = (acc[rt][nt][reg] + bv[nt]) * scale;
          int m = mb * 128 + wr * 64 + rt * 16 + 4 * quad + reg;
          int n = nbm * 128 + wc * 64 + nt * 16 + c;
          int b = m >> 11, s = m & 2047, h = n >> 6, d = n & 63;
          dst[(((size_t)b * 16 + h) * 2048 + s) * 64 + d] = (bf16)v;
        }
  }
}

// ---------------------------------------------------------------------------
// Kernel 2: attention, KEY-SPLIT across waves. r7 diagnosis: at 4 waves/SIMD
// the shared-tile design is LDS-read-saturated (16 waves x 16KB/iter ~ 250
// B/cyc ~ port limit); at 2 waves/SIMD it's latency-bound -- both walls at
// ~54us. Fix: wave w takes key-half (w&1, 32 keys) x q-half (w>>1, 32 rows)
// of the WG's 64x64 job -> K reads 4KB + V reads 4KB per wave-iter (8 b128,
// was 16). MFMA count unchanged (8 QK + 8 PV, PV at full K=32). Quad
// transpose: pf B-frag needs keys 8*quad+j; sources s[g][kt2] hold keys
// 16*kt2+4*quad+reg; (pw0,pw2)=pl16swap(pl32swap(A,B)) per dword pair --
// isomorphic to the verified r7 sequence. Partial O/lsum combined across
// wave-pairs once in the epilogue via LDS (dead K/V space). Grid 1024 WGs,
// 256 thr, 40KB -> 4 WG/CU = 4 waves/SIMD kept. VGPR ~100 <= 128.
// ---------------------------------------------------------------------------
__global__ __launch_bounds__(256, 4)
void attn(const bf16* __restrict__ qg, const bf16* __restrict__ kg,
          const bf16* __restrict__ vtg, const float* __restrict__ mask,
          float* __restrict__ out) {
  const int blk = blockIdx.x;                // 0..1023
  const int xcd = blk & 7, slot = blk >> 3;  // slot 0..127
  const int bh = xcd * 4 + (slot >> 5);      // 4 bh per XCD (K/V pinned in L2)
  const int qblk = slot & 31;                // 32 qblks x 64 rows
  const int b = bh >> 4, h = bh & 15;
  const int tid = threadIdx.x;
  const int wave = tid >> 6, lane = tid & 63, quad = lane >> 4, c = lane & 15;
  const int w2 = wave & 1;                   // key-half of the 64-key tile
  const int wq = wave >> 1;                  // q-half of the 64 q-rows
  const int lrow = lane >> 3, lg = (lane & 7) ^ lrow;

  // pool: [K dbuf 16KB][V dbuf 16KB][mask 8KB]; epilogue reuses [0,18KB)
  __shared__ __align__(16) unsigned char SH[40960];
  float* Ms = (float*)(SH + 32768);

  const bf16* qb_ = qg + (size_t)bh * 2048 * 64;
  const bf16* kb_ = kg + (size_t)bh * 2048 * 64;
  const bf16* vb_ = vtg + (size_t)bh * 64 * 2048;

  // ---- prologue: mask -> LDS (pre-scaled), Q frags, stage tile 0 ----
  #pragma unroll
  for (int i = 0; i < 2; ++i) {
    int idx = i * 1024 + tid * 4;
    float4 m = *(const float4*)&mask[b * 2048 + idx];
    float4 ms = {m.x * LOG2E, m.y * LOG2E, m.z * LOG2E, m.w * LOG2E};
    *(float4*)&Ms[idx] = ms;
  }

  bf16x8 qf[2][2];   // [g][ch]; wave covers q rows qblk*64 + wq*32 + g*16 + c
  #pragma unroll
  for (int g = 0; g < 2; ++g)
    #pragma unroll
    for (int ch = 0; ch < 2; ++ch)
      qf[g][ch] = *(const bf16x8*)(qb_ +
          (size_t)(qblk * 64 + wq * 32 + g * 16 + c) * 64 + ch * 32 + quad * 8);

  #pragma unroll
  for (int i = 0; i < 2; ++i) {   // wave stages 16 K rows + 16 V rows of tile 0
    int r = wave * 16 + i * 8;
    stage16(kb_ + (size_t)(r + lrow) * 64 + lg * 8, (bf16*)SH + r * 64);
    stage16(vb_ + (size_t)(r + lrow) * 2048 + lg * 8, (bf16*)(SH + 16384) + r * 64);
  }
  __asm__ volatile("s_waitcnt lgkmcnt(0)" ::: "memory");  // mask ds_writes done

  f32x4 o[4][2] = {};       // o[dt][g][reg] = O^T[d=dt*16+4*quad+reg][q] partial
  float lsum[2] = {0.f, 0.f};

  for (int kt = 0; kt < 32; ++kt) {
    const int cur = kt & 1;
    bf16* Kc = (bf16*)(SH + cur * 8192);
    bf16* Vc = (bf16*)(SH + 16384 + cur * 8192);
    // own stage(kt) loads are the only outstanding VMEM: drain (1 iter cover)
    __asm__ volatile("s_waitcnt vmcnt(0)" ::: "memory");
    __builtin_amdgcn_s_barrier();
    __builtin_amdgcn_sched_barrier(0);   // nothing hoists above the barrier

    if (kt < 31) {                       // stage tile kt+1 into the other buf
      bf16* Kn = (bf16*)(SH + (cur ^ 1) * 8192);
      bf16* Vn = (bf16*)(SH + 16384 + (cur ^ 1) * 8192);
      #pragma unroll
      for (int i = 0; i < 2; ++i) {
        int r = wave * 16 + i * 8;
        stage16(kb_ + (size_t)((kt + 1) * 64 + r + lrow) * 64 + lg * 8, Kn + r * 64);
        stage16(vb_ + (size_t)(r + lrow) * 2048 + (kt + 1) * 64 + lg * 8, Vn + r * 64);
      }
    }
    __builtin_amdgcn_sched_barrier(0);   // staging issued before compute

    // ---- seed S^T accumulators with mask (key-indexed; same for both g) ----
    f32x4 s[2][2];   // [g][kt2]: key = w2*32 + kt2*16 + 4*quad + reg, q-group g
    #pragma unroll
    for (int kt2 = 0; kt2 < 2; ++kt2) {
      float4 mv = *(const float4*)&Ms[kt * 64 + w2 * 32 + kt2 * 16 + 4 * quad];
      f32x4 sv = {mv.x, mv.y, mv.z, mv.w};
      s[0][kt2] = sv;
      s[1][kt2] = sv;
    }

    // ---- S^T = K Q^T + mask (wave's 32 keys x its 32 q-rows) ----
    __builtin_amdgcn_s_setprio(1);
    #pragma unroll
    for (int kt2 = 0; kt2 < 2; ++kt2)
      #pragma unroll
      for (int ch = 0; ch < 2; ++ch) {
        bf16x8 kf = *(const bf16x8*)&Kc[(w2 * 32 + kt2 * 16 + c) * 64 +
                                        ((((ch << 2) | quad) ^ (c & 7)) << 3)];
        s[0][kt2] = MFMA(kf, qf[0][ch], s[0][kt2]);
        s[1][kt2] = MFMA(kf, qf[1][ch], s[1][kt2]);
      }
    __builtin_amdgcn_s_setprio(0);

    // ---- p = exp2(s); pack; quad-transpose -> pf[g] = B-frag keys 8*quad+j
    // (pw0,pw2) = pl16swap(pl32swap(A0,B0)); (pw1,pw3) likewise on dw1.
    bf16x8 pf[2];
    #pragma unroll
    for (int g = 0; g < 2; ++g) {
      unsigned int A0, A1, B0, B1;
      {
        bf16x4 pk;
        #pragma unroll
        for (int reg = 0; reg < 4; ++reg) {
          float p = __builtin_amdgcn_exp2f(s[g][0][reg]);
          lsum[g] += p;
          pk[reg] = (bf16)p;
        }
        uint2v uu = __builtin_bit_cast(uint2v, pk);
        A0 = uu.x; A1 = uu.y;
      }
      {
        bf16x4 pk;
        #pragma unroll
        for (int reg = 0; reg < 4; ++reg) {
          float p = __builtin_amdgcn_exp2f(s[g][1][reg]);
          lsum[g] += p;
          pk[reg] = (bf16)p;
        }
        uint2v uu = __builtin_bit_cast(uint2v, pk);
        B0 = uu.x; B1 = uu.y;
      }
      __asm__ volatile("v_permlane32_swap_b32 %0, %1" : "+v"(A0), "+v"(B0));
      __asm__ volatile("v_permlane32_swap_b32 %0, %1" : "+v"(A1), "+v"(B1));
      __asm__ volatile("v_permlane16_swap_b32 %0, %1" : "+v"(A0), "+v"(B0));
      __asm__ volatile("v_permlane16_swap_b32 %0, %1" : "+v"(A1), "+v"(B1));
      uint4v up = {A0, A1, B0, B1};
      pf[g] = __builtin_bit_cast(bf16x8, up);
    }

    // ---- O^T += V^T P^T (A = V^T frag, keys 8*quad+j of wave's half) ----
    __builtin_amdgcn_s_setprio(1);
    #pragma unroll
    for (int dt = 0; dt < 4; ++dt) {
      bf16x8 vf = *(const bf16x8*)&Vc[(dt * 16 + c) * 64 +
                                      ((((w2 << 2) | quad) ^ (c & 7)) << 3)];
      o[dt][0] = MFMA(vf, pf[0], o[dt][0]);
      o[dt][1] = MFMA(vf, pf[1], o[dt][1]);
    }
    __builtin_amdgcn_s_setprio(0);
  }

  // ---- quad-reduce lsum: sum over this wave's 32 keys for q = ..+16g+c ----
  #pragma unroll
  for (int g = 0; g < 2; ++g) {
    lsum[g] += __shfl_xor(lsum[g], 16, 64);
    lsum[g] += __shfl_xor(lsum[g], 32, 64);
  }

  // ---- cross-wave combine: w2=1 waves write partials; w2=0 add+normalize ----
  __syncthreads();
  float* rec = (float*)(SH + (size_t)(wq * 64 + lane) * 144);
  if (w2 == 1) {
    #pragma unroll
    for (int dt = 0; dt < 4; ++dt)
      #pragma unroll
      for (int g = 0; g < 2; ++g)
        *(f32x4*)&rec[(dt * 2 + g) * 4] = o[dt][g];
    rec[32] = lsum[0];
    rec[33] = lsum[1];
  }
  __syncthreads();
  if (w2 == 0) {
    float inv[2];
    #pragma unroll
    for (int g = 0; g < 2; ++g) inv[g] = 1.0f / (lsum[g] + rec[32 + g]);
    #pragma unroll
    for (int dt = 0; dt < 4; ++dt)
      #pragma unroll
      for (int g = 0; g < 2; ++g) {
        f32x4 po = *(const f32x4*)&rec[(dt * 2 + g) * 4];
        const int srow = qblk * 64 + wq * 32 + g * 16 + c;
        float4 st = { (o[dt][g][0] + po[0]) * inv[g],
                      (o[dt][g][1] + po[1]) * inv[g],
                      (o[dt][g][2] + po[2]) * inv[g],
                      (o[dt][g][3] + po[3]) * inv[g] };
        *(float4*)&out[((size_t)b * 2048 + srow) * 1024 + h * 64 + dt * 16 + 4 * quad] = st;
      }
  }
}

// ---------------------------------------------------------------------------
extern "C" void kernel_launch(void* const* d_in, const int* in_sizes, int n_in,
                              void* d_out, int out_size, void* d_ws, size_t ws_size,
                              hipStream_t stream) {
  const float* hs   = (const float*)d_in[0];
  const float* mask = (const float*)d_in[1];
  const float* qw   = (const float*)d_in[2];
  const float* qb   = (const float*)d_in[3];
  const float* kw   = (const float*)d_in[4];
  const float* kb   = (const float*)d_in[5];
  const float* vw   = (const float*)d_in[6];
  const float* vb   = (const float*)d_in[7];
  float* out = (float*)d_out;

  bf16* Xb   = (bf16*)d_ws;                       // 4096x1024      (8 MB)
  bf16* Wt   = Xb + (size_t)4096 * 1024;          // 3x1024x1024    (6 MB)
  bf16* q_ws = Wt + (size_t)3 * 1048576;          // [B,H,S,64]     (8 MB)
  bf16* k_ws = q_ws + (size_t)4096 * 1024;        // [B,H,S,64]     (8 MB)
  bf16* v_ws = k_ws + (size_t)4096 * 1024;        // [B,H,64,S] V^T (8 MB)

  cvt<<<dim3(2816), 256, 0, stream>>>(hs, qw, kw, vw, Xb, Wt);
  qkv_gemm<<<dim3(768), 256, 0, stream>>>(Xb, Wt, qb, kb, vb, q_ws, k_ws, v_ws);
  attn<<<dim3(1024), 256, 0, stream>>>(q_ws, k_ws, v_ws, mask, out);
}